// Round 1
// baseline (1507.623 us; speedup 1.0000x reference)
//
#include <hip/hip_runtime.h>
#include <cstdint>
#include <cstddef>

using u16 = unsigned short;
using bf16x8 = __attribute__((ext_vector_type(8))) __bf16;
using f32x4  = __attribute__((ext_vector_type(4))) float;

constexpr int Bb = 2, Tt = 4096, Cc = 2048, Hh = 16, Dd = 128;
constexpr int Mm = Bb * Tt;   // 8192 rows
constexpr float EPSf = 1e-5f;

__device__ __forceinline__ u16 f2bf(float f) {
  union { float f; uint32_t u; } v; v.f = f;
  return (u16)((v.u + 0x7fffu + ((v.u >> 16) & 1u)) >> 16);  // RNE
}
__device__ __forceinline__ float bf2f(u16 h) {
  union { uint32_t u; float f; } v; v.u = ((uint32_t)h) << 16;
  return v.f;
}
__device__ __forceinline__ float sig_(float z) { return 1.f / (1.f + __expf(-z)); }
__device__ __forceinline__ float wred(float v) {
#pragma unroll
  for (int m = 32; m; m >>= 1) v += __shfl_xor(v, m);
  return v;
}

// ---------------- conv (causal depthwise K=4) + silu + bf16 casts ----------
__global__ void la_conv(const float* __restrict__ x, const float* __restrict__ cw,
                        const float* __restrict__ cb, u16* __restrict__ xbf,
                        u16* __restrict__ xconv) {
  int idx = blockIdx.x * 256 + threadIdx.x;        // < Mm*Cc, c fastest
  int c = idx & (Cc - 1);
  int bt = idx >> 11;                              // /Cc
  int t = bt & (Tt - 1);
  float xv = x[idx];
  xbf[idx] = f2bf(xv);
  float4 w = ((const float4*)cw)[c];               // conv_w[c][0][0..3]
  float acc = cb[c] + w.w * xv;                    // j=3 multiplies x[t]
  if (t >= 1) acc += w.z * x[idx - Cc];
  if (t >= 2) acc += w.y * x[idx - 2 * Cc];
  if (t >= 3) acc += w.x * x[idx - 3 * Cc];
  float s = acc * sig_(acc);                       // silu
  xconv[idx] = f2bf(s);
}

// ---------------- fp32 -> bf16 convert (weights) ---------------------------
__global__ void la_cvt(const float* __restrict__ in, u16* __restrict__ out, int n4) {
  int i = blockIdx.x * 256 + threadIdx.x;
  if (i < n4) {
    float4 v = ((const float4*)in)[i];
    ushort4 o;
    o.x = f2bf(v.x); o.y = f2bf(v.y); o.z = f2bf(v.z); o.w = f2bf(v.w);
    ((ushort4*)out)[i] = o;
  }
}

// ---------------- gamma = sigmoid(xconv @ Wgam.T + bgam) -------------------
// one wave per (row,h) pair; lane covers 8 contiguous k, 4 strided chunks
__global__ void la_gamma(const u16* __restrict__ xconv, const float* __restrict__ Wg,
                         const float* __restrict__ bg, float* __restrict__ gam) {
  const int wave = threadIdx.x >> 6, lane = threadIdx.x & 63;
  const int p = blockIdx.x * 4 + wave;             // < Mm*Hh
  const int row = p >> 4, h = p & 15;
  const u16* xr = xconv + (size_t)row * Cc;
  const float* wr = Wg + (size_t)h * Cc;
  float acc = 0.f;
#pragma unroll
  for (int it = 0; it < 4; it++) {
    int k = lane * 8 + it * 512;
    bf16x8 xv = *(const bf16x8*)(xr + k);
    float4 w0 = *(const float4*)(wr + k);
    float4 w1 = *(const float4*)(wr + k + 4);
    acc += (float)xv[0]*w0.x + (float)xv[1]*w0.y + (float)xv[2]*w0.z + (float)xv[3]*w0.w;
    acc += (float)xv[4]*w1.x + (float)xv[5]*w1.y + (float)xv[6]*w1.z + (float)xv[7]*w1.w;
  }
  acc = wred(acc);
  if (lane == 0) gam[p] = sig_(acc + bg[h]);
}

// ---------------- prep: q=l2norm, k=l2norm, v=LN, ig=sigmoid, kv=ig*k*v ----
// one wave per (row,h); lane holds d = 2*lane, 2*lane+1
__global__ void la_prep(const u16* pq, const u16* pk, const u16* pv, const u16* pig,
                        const float* __restrict__ vng, const float* __restrict__ vnb,
                        const float* __restrict__ bigv, u16* qo, u16* kvo) {
  const int wave = threadIdx.x >> 6, lane = threadIdx.x & 63;
  const int p = blockIdx.x * 4 + wave;
  const int row = p >> 4, h = p & 15;
  const int d0 = lane * 2;
  const size_t base = (size_t)row * Cc + h * Dd + d0;
  uint32_t uq = *(const uint32_t*)(pq + base);
  uint32_t uk = *(const uint32_t*)(pk + base);
  uint32_t uv = *(const uint32_t*)(pv + base);
  uint32_t ui = *(const uint32_t*)(pig + base);
  float q0 = bf2f((u16)uq), q1 = bf2f((u16)(uq >> 16));
  float k0 = bf2f((u16)uk), k1 = bf2f((u16)(uk >> 16));
  float v0 = bf2f((u16)uv), v1 = bf2f((u16)(uv >> 16));
  float i0 = bf2f((u16)ui), i1 = bf2f((u16)(ui >> 16));
  float qs = wred(q0*q0 + q1*q1);
  float ks = wred(k0*k0 + k1*k1);
  float s1 = wred(v0 + v1);
  float s2 = wred(v0*v0 + v1*v1);
  float qn = 1.f / fmaxf(sqrtf(qs), 1e-12f);
  float kn = 1.f / fmaxf(sqrtf(ks), 1e-12f);
  float mu = s1 * (1.f / Dd);
  float var = s2 * (1.f / Dd) - mu * mu;
  float rs = rsqrtf(var + EPSf);
  int c0 = h * Dd + d0;
  float vh0 = (v0 - mu) * rs * vng[d0]     + vnb[d0];
  float vh1 = (v1 - mu) * rs * vng[d0 + 1] + vnb[d0 + 1];
  float ig0 = sig_(i0 + bigv[c0]);
  float ig1 = sig_(i1 + bigv[c0 + 1]);
  float kv0 = ig0 * (k0 * kn) * vh0;
  float kv1 = ig1 * (k1 * kn) * vh1;
  *(uint32_t*)(qo + base)  = (uint32_t)f2bf(q0 * qn) | ((uint32_t)f2bf(q1 * qn) << 16);
  *(uint32_t*)(kvo + base) = (uint32_t)f2bf(kv0)     | ((uint32_t)f2bf(kv1) << 16);
}

// ---------------- scan: mem_t = gamma_t * mem_{t-1} + kv_t (in-place) ------
// one 64-thread block per (b,h); lane holds d = 2*lane, 2*lane+1
__global__ void la_scan(const u16* __restrict__ kvin, u16* __restrict__ memo,
                        const float* __restrict__ gam) {
  const int bh = blockIdx.x;           // < Bb*Hh
  const int b = bh >> 4, h = bh & 15;
  const int lane = threadIdx.x;
  const size_t base = ((size_t)b * Tt) * Cc + h * Dd + lane * 2;
  const float* gp = gam + ((size_t)b * Tt) * Hh + h;
  float m0 = 0.f, m1 = 0.f;
#pragma unroll 4
  for (int t = 0; t < Tt; t++) {
    float g = gp[(size_t)t * Hh];
    uint32_t u = *(const uint32_t*)(kvin + base + (size_t)t * Cc);
    m0 = fmaf(g, m0, bf2f((u16)u));
    m1 = fmaf(g, m1, bf2f((u16)(u >> 16)));
    *(uint32_t*)(memo + base + (size_t)t * Cc) =
        (uint32_t)f2bf(m0) | ((uint32_t)f2bf(m1) << 16);
  }
}

// ---------------- post: LN(mem)*q -> GroupNorm -> *sigmoid(og) -------------
__global__ void la_post(const u16* mem, const u16* q, const u16* ogp,
                        const float* __restrict__ mng, const float* __restrict__ mnb,
                        const float* __restrict__ gng, const float* __restrict__ gnb,
                        const float* __restrict__ bog, u16* outb) {
  const int wave = threadIdx.x >> 6, lane = threadIdx.x & 63;
  const int p = blockIdx.x * 4 + wave;
  const int row = p >> 4, h = p & 15;
  const int d0 = lane * 2;
  const size_t base = (size_t)row * Cc + h * Dd + d0;
  uint32_t um = *(const uint32_t*)(mem + base);
  uint32_t uq = *(const uint32_t*)(q + base);
  uint32_t uo = *(const uint32_t*)(ogp + base);
  float m0 = bf2f((u16)um), m1 = bf2f((u16)(um >> 16));
  float q0 = bf2f((u16)uq), q1 = bf2f((u16)(uq >> 16));
  float g0 = bf2f((u16)uo), g1 = bf2f((u16)(uo >> 16));
  float s1 = wred(m0 + m1);
  float s2 = wred(m0*m0 + m1*m1);
  float mu = s1 * (1.f / Dd);
  float var = s2 * (1.f / Dd) - mu * mu;
  float rs = rsqrtf(var + EPSf);
  int c0 = h * Dd + d0;
  float mo0 = (m0 - mu) * rs * mng[d0]     + mnb[d0];
  float mo1 = (m1 - mu) * rs * mng[d0 + 1] + mnb[d0 + 1];
  float o0 = mo0 * q0, o1 = mo1 * q1;
  float t1 = wred(o0 + o1);
  float t2 = wred(o0*o0 + o1*o1);
  float mu2 = t1 * (1.f / Dd);
  float var2 = t2 * (1.f / Dd) - mu2 * mu2;
  float rs2 = rsqrtf(var2 + EPSf);
  float y0 = (o0 - mu2) * rs2 * gng[c0]     + gnb[c0];
  float y1 = (o1 - mu2) * rs2 * gng[c0 + 1] + gnb[c0 + 1];
  y0 *= sig_(g0 + bog[c0]);
  y1 *= sig_(g1 + bog[c0 + 1]);
  *(uint32_t*)(outb + base) = (uint32_t)f2bf(y0) | ((uint32_t)f2bf(y1) << 16);
}

// ---------------- GEMM: C[M,N] = A[M,K] @ W[N,K]^T, bf16 in, fp32 acc ------
#define BMt 128
#define BNt 128
#define BKt 32
#define LDK 40   // padded row stride (elems): 80 B = 5*16B -> aligned b128 reads

template <int OUT_BF16>
__global__ __launch_bounds__(256)
void la_gemm(const u16* __restrict__ A, const u16* __restrict__ W,
             void* __restrict__ Co, int M, int N, int K) {
  __shared__ u16 As[BMt * LDK];
  __shared__ u16 Bs[BNt * LDK];
  const int tid = threadIdx.x;
  const int lane = tid & 63;
  const int wave = tid >> 6;
  const int bm = blockIdx.x * BMt;
  const int bn = blockIdx.y * BNt;
  const int wm = (wave >> 1) * 64;       // 2x2 wave grid, each 64x64
  const int wn = (wave & 1) * 64;
  const int fm = lane & 15;              // frag row within 16
  const int fko = (lane >> 4) * 8;       // frag k offset (quad*8)
  const int sr = tid >> 1;               // staging row 0..127
  const int sk = (tid & 1) * 16;         // staging k offset 0/16

  const u16* Ag = A + (size_t)(bm + sr) * K + sk;
  const u16* Wg = W + (size_t)(bn + sr) * K + sk;
  u16* Asw = &As[sr * LDK + sk];
  u16* Bsw = &Bs[sr * LDK + sk];

  f32x4 acc[4][4] = {};

  for (int k0 = 0; k0 < K; k0 += BKt) {
    uint4 a0 = *(const uint4*)(Ag + k0);
    uint4 a1 = *(const uint4*)(Ag + k0 + 8);
    uint4 b0 = *(const uint4*)(Wg + k0);
    uint4 b1 = *(const uint4*)(Wg + k0 + 8);
    __syncthreads();
    *(uint4*)Asw = a0;  *(uint4*)(Asw + 8) = a1;
    *(uint4*)Bsw = b0;  *(uint4*)(Bsw + 8) = b1;
    __syncthreads();
    bf16x8 af[4], bfr[4];
#pragma unroll
    for (int i = 0; i < 4; i++)
      af[i] = *(const bf16x8*)&As[(wm + i * 16 + fm) * LDK + fko];
#pragma unroll
    for (int j = 0; j < 4; j++)
      bfr[j] = *(const bf16x8*)&Bs[(wn + j * 16 + fm) * LDK + fko];
#pragma unroll
    for (int i = 0; i < 4; i++)
#pragma unroll
      for (int j = 0; j < 4; j++)
        acc[i][j] = __builtin_amdgcn_mfma_f32_16x16x32_bf16(af[i], bfr[j], acc[i][j], 0, 0, 0);
  }

  // C/D layout: row = (lane>>4)*4 + r, col = lane&15
  const int cr = (lane >> 4) * 4;
  const int cc = lane & 15;
#pragma unroll
  for (int i = 0; i < 4; i++) {
#pragma unroll
    for (int j = 0; j < 4; j++) {
#pragma unroll
      for (int r = 0; r < 4; r++) {
        size_t off = (size_t)(bm + wm + i * 16 + cr + r) * N + (bn + wn + j * 16 + cc);
        if (OUT_BF16) ((u16*)Co)[off] = f2bf(acc[i][j][r]);
        else          ((float*)Co)[off] = acc[i][j][r];
      }
    }
  }
}

// ---------------- launcher -------------------------------------------------
extern "C" void kernel_launch(void* const* d_in, const int* in_sizes, int n_in,
                              void* d_out, int out_size, void* d_ws, size_t ws_size,
                              hipStream_t stream) {
  (void)in_sizes; (void)n_in; (void)out_size; (void)ws_size;
  const float* x    = (const float*)d_in[0];
  const float* Wq   = (const float*)d_in[1];
  const float* Wk   = (const float*)d_in[2];
  const float* Wv   = (const float*)d_in[3];
  const float* Wo   = (const float*)d_in[4];
  const float* cw   = (const float*)d_in[5];
  const float* cb   = (const float*)d_in[6];
  const float* Wig  = (const float*)d_in[7];
  const float* big  = (const float*)d_in[8];
  const float* Wog  = (const float*)d_in[9];
  const float* bog  = (const float*)d_in[10];
  const float* Wgam = (const float*)d_in[11];
  const float* bgam = (const float*)d_in[12];
  const float* vng  = (const float*)d_in[13];
  const float* vnb  = (const float*)d_in[14];
  const float* mng  = (const float*)d_in[15];
  const float* mnb  = (const float*)d_in[16];
  const float* gng  = (const float*)d_in[17];
  const float* gnb  = (const float*)d_in[18];

  char* ws = (char*)d_ws;
  const size_t NB = (size_t)Mm * Cc * 2;          // 33,554,432 B per bf16 buffer
  u16* xbf   = (u16*)(ws + 0 * NB);               // x bf16, later out1 bf16
  u16* xconv = (u16*)(ws + 1 * NB);               // silu(conv) bf16
  u16* preq  = (u16*)(ws + 2 * NB);               // q_pre -> q
  u16* prek  = (u16*)(ws + 3 * NB);               // k_pre -> kv -> mem
  u16* prev  = (u16*)(ws + 4 * NB);               // v_pre -> og_pre
  u16* preig = (u16*)(ws + 5 * NB);               // ig_pre
  u16* wbf   = (u16*)(ws + 6 * NB);               // one bf16 weight slot (reused)
  float* gam = (float*)(ws + 6 * NB + (size_t)Cc * Cc * 2);  // [Mm][Hh] fp32

  const int NX  = Mm * Cc;        // 16,777,216
  const int WN4 = Cc * Cc / 4;    // 1,048,576
  dim3 blk(256);
  dim3 ggrid(Mm / BMt, Cc / BNt); // (64,16)

  la_conv<<<NX / 256, blk, 0, stream>>>(x, cw, cb, xbf, xconv);

  la_cvt<<<WN4 / 256, blk, 0, stream>>>(Wq, wbf, WN4);
  la_gemm<1><<<ggrid, blk, 0, stream>>>(xbf, wbf, (void*)preq, Mm, Cc, Cc);
  la_cvt<<<WN4 / 256, blk, 0, stream>>>(Wk, wbf, WN4);
  la_gemm<1><<<ggrid, blk, 0, stream>>>(xbf, wbf, (void*)prek, Mm, Cc, Cc);
  la_cvt<<<WN4 / 256, blk, 0, stream>>>(Wv, wbf, WN4);
  la_gemm<1><<<ggrid, blk, 0, stream>>>(xbf, wbf, (void*)prev, Mm, Cc, Cc);
  la_cvt<<<WN4 / 256, blk, 0, stream>>>(Wig, wbf, WN4);
  la_gemm<1><<<ggrid, blk, 0, stream>>>(xconv, wbf, (void*)preig, Mm, Cc, Cc);

  la_gamma<<<Mm * Hh / 4, blk, 0, stream>>>(xconv, Wgam, bgam, gam);

  la_prep<<<Mm * Hh / 4, blk, 0, stream>>>(preq, prek, prev, preig,
                                           vng, vnb, big, preq, prek);

  la_cvt<<<WN4 / 256, blk, 0, stream>>>(Wog, wbf, WN4);
  la_gemm<1><<<ggrid, blk, 0, stream>>>(xconv, wbf, (void*)prev, Mm, Cc, Cc);

  la_scan<<<Bb * Hh, dim3(64), 0, stream>>>(prek, prek, gam);

  la_post<<<Mm * Hh / 4, blk, 0, stream>>>(prek, preq, prev,
                                           mng, mnb, gng, gnb, bog, xbf);

  la_cvt<<<WN4 / 256, blk, 0, stream>>>(Wo, wbf, WN4);
  la_gemm<0><<<ggrid, blk, 0, stream>>>(xbf, wbf, d_out, Mm, Cc, Cc);
}

// Round 2
// 1044.944 us; speedup vs baseline: 1.4428x; 1.4428x over previous
//
#include <hip/hip_runtime.h>
#include <cstdint>
#include <cstddef>

using u16 = unsigned short;
using bf16x8 = __attribute__((ext_vector_type(8))) __bf16;
using f32x4  = __attribute__((ext_vector_type(4))) float;

constexpr int Bb = 2, Tt = 4096, Cc = 2048, Hh = 16, Dd = 128;
constexpr int Mm = Bb * Tt;   // 8192 rows
constexpr int CHK = 64;       // scan chunk length
constexpr int NCH = Tt / CHK; // 64 chunks per (b,h)
constexpr float EPSf = 1e-5f;

__device__ __forceinline__ u16 f2bf(float f) {
  union { float f; uint32_t u; } v; v.f = f;
  return (u16)((v.u + 0x7fffu + ((v.u >> 16) & 1u)) >> 16);  // RNE
}
__device__ __forceinline__ float bf2f(u16 h) {
  union { uint32_t u; float f; } v; v.u = ((uint32_t)h) << 16;
  return v.f;
}
__device__ __forceinline__ float sig_(float z) { return 1.f / (1.f + __expf(-z)); }
__device__ __forceinline__ float wred(float v) {
#pragma unroll
  for (int m = 32; m; m >>= 1) v += __shfl_xor(v, m);
  return v;
}
__device__ __forceinline__ void glds16(const u16* g, u16* l) {
  __builtin_amdgcn_global_load_lds(
      (const __attribute__((address_space(1))) unsigned int*)g,
      (__attribute__((address_space(3))) unsigned int*)l, 16, 0, 0);
}

// ---------------- conv (causal depthwise K=4) + silu + bf16 casts ----------
__global__ void la_conv(const float* __restrict__ x, const float* __restrict__ cw,
                        const float* __restrict__ cb, u16* __restrict__ xbf,
                        u16* __restrict__ xconv) {
  int idx = blockIdx.x * 256 + threadIdx.x;        // < Mm*Cc, c fastest
  int c = idx & (Cc - 1);
  int bt = idx >> 11;                              // /Cc
  int t = bt & (Tt - 1);
  float xv = x[idx];
  xbf[idx] = f2bf(xv);
  float4 w = ((const float4*)cw)[c];               // conv_w[c][0][0..3]
  float acc = cb[c] + w.w * xv;                    // j=3 multiplies x[t]
  if (t >= 1) acc += w.z * x[idx - Cc];
  if (t >= 2) acc += w.y * x[idx - 2 * Cc];
  if (t >= 3) acc += w.x * x[idx - 3 * Cc];
  float s = acc * sig_(acc);                       // silu
  xconv[idx] = f2bf(s);
}

// ---------------- fp32 -> bf16 convert (weights) ---------------------------
__global__ void la_cvt(const float* __restrict__ in, u16* __restrict__ out, int n4) {
  int i = blockIdx.x * 256 + threadIdx.x;
  if (i < n4) {
    float4 v = ((const float4*)in)[i];
    ushort4 o;
    o.x = f2bf(v.x); o.y = f2bf(v.y); o.z = f2bf(v.z); o.w = f2bf(v.w);
    ((ushort4*)out)[i] = o;
  }
}

// ---------------- gamma = sigmoid(xconv @ Wgam.T + bgam) -------------------
__global__ void la_gamma(const u16* __restrict__ xconv, const float* __restrict__ Wg,
                         const float* __restrict__ bg, float* __restrict__ gam) {
  const int wave = threadIdx.x >> 6, lane = threadIdx.x & 63;
  const int p = blockIdx.x * 4 + wave;             // < Mm*Hh
  const int row = p >> 4, h = p & 15;
  const u16* xr = xconv + (size_t)row * Cc;
  const float* wr = Wg + (size_t)h * Cc;
  float acc = 0.f;
#pragma unroll
  for (int it = 0; it < 4; it++) {
    int k = lane * 8 + it * 512;
    bf16x8 xv = *(const bf16x8*)(xr + k);
    float4 w0 = *(const float4*)(wr + k);
    float4 w1 = *(const float4*)(wr + k + 4);
    acc += (float)xv[0]*w0.x + (float)xv[1]*w0.y + (float)xv[2]*w0.z + (float)xv[3]*w0.w;
    acc += (float)xv[4]*w1.x + (float)xv[5]*w1.y + (float)xv[6]*w1.z + (float)xv[7]*w1.w;
  }
  acc = wred(acc);
  if (lane == 0) gam[p] = sig_(acc + bg[h]);
}

// ---------------- prep: q=l2norm, k=l2norm, v=LN, ig=sigmoid, kv=ig*k*v ----
__global__ void la_prep(const u16* pq, const u16* pk, const u16* pv, const u16* pig,
                        const float* __restrict__ vng, const float* __restrict__ vnb,
                        const float* __restrict__ bigv, u16* qo, u16* kvo) {
  const int wave = threadIdx.x >> 6, lane = threadIdx.x & 63;
  const int p = blockIdx.x * 4 + wave;
  const int row = p >> 4, h = p & 15;
  const int d0 = lane * 2;
  const size_t base = (size_t)row * Cc + h * Dd + d0;
  uint32_t uq = *(const uint32_t*)(pq + base);
  uint32_t uk = *(const uint32_t*)(pk + base);
  uint32_t uv = *(const uint32_t*)(pv + base);
  uint32_t ui = *(const uint32_t*)(pig + base);
  float q0 = bf2f((u16)uq), q1 = bf2f((u16)(uq >> 16));
  float k0 = bf2f((u16)uk), k1 = bf2f((u16)(uk >> 16));
  float v0 = bf2f((u16)uv), v1 = bf2f((u16)(uv >> 16));
  float i0 = bf2f((u16)ui), i1 = bf2f((u16)(ui >> 16));
  float qs = wred(q0*q0 + q1*q1);
  float ks = wred(k0*k0 + k1*k1);
  float s1 = wred(v0 + v1);
  float s2 = wred(v0*v0 + v1*v1);
  float qn = 1.f / fmaxf(sqrtf(qs), 1e-12f);
  float kn = 1.f / fmaxf(sqrtf(ks), 1e-12f);
  float mu = s1 * (1.f / Dd);
  float var = s2 * (1.f / Dd) - mu * mu;
  float rs = rsqrtf(var + EPSf);
  int c0 = h * Dd + d0;
  float vh0 = (v0 - mu) * rs * vng[d0]     + vnb[d0];
  float vh1 = (v1 - mu) * rs * vng[d0 + 1] + vnb[d0 + 1];
  float ig0 = sig_(i0 + bigv[c0]);
  float ig1 = sig_(i1 + bigv[c0 + 1]);
  float kv0 = ig0 * (k0 * kn) * vh0;
  float kv1 = ig1 * (k1 * kn) * vh1;
  *(uint32_t*)(qo + base)  = (uint32_t)f2bf(q0 * qn) | ((uint32_t)f2bf(q1 * qn) << 16);
  *(uint32_t*)(kvo + base) = (uint32_t)f2bf(kv0)     | ((uint32_t)f2bf(kv1) << 16);
}

// ---------------- scan phase 1: local chunk scans --------------------------
// wave p = bh*NCH + c; lane holds d = 2*lane, 2*lane+1
// writes: local mem (bf16, in-place over kv), cumgamma (fp32, in-place over gam),
//         chunk-end state E (fp32)
__global__ void la_scan1(u16* __restrict__ kv, float* __restrict__ gam,
                         float* __restrict__ Ebuf) {
  const int wave = threadIdx.x >> 6, lane = threadIdx.x & 63;
  const int p = blockIdx.x * 4 + wave;           // < Bb*Hh*NCH
  const int bh = p >> 6, c = p & (NCH - 1);
  const int b = bh >> 4, h = bh & 15;
  const int t0 = c * CHK;
  const size_t rbase = (size_t)b * Tt + t0;      // first global row of chunk
  const size_t base = rbase * Cc + h * Dd + lane * 2;
  float* gp = gam + rbase * Hh + h;
  float m0 = 0.f, m1 = 0.f, cg = 1.f;
#pragma unroll 4
  for (int t = 0; t < CHK; t++) {
    float g = gp[(size_t)t * Hh];
    cg *= g;
    uint32_t u = *(const uint32_t*)(kv + base + (size_t)t * Cc);
    m0 = fmaf(g, m0, bf2f((u16)u));
    m1 = fmaf(g, m1, bf2f((u16)(u >> 16)));
    *(uint32_t*)(kv + base + (size_t)t * Cc) =
        (uint32_t)f2bf(m0) | ((uint32_t)f2bf(m1) << 16);
    if (lane == 0) gp[(size_t)t * Hh] = cg;      // cumgamma from chunk start
  }
  float2 e; e.x = m0; e.y = m1;
  *(float2*)&Ebuf[(size_t)p * Dd + lane * 2] = e;
}

// ---------------- scan phase 2: carry across chunks ------------------------
// one 64-thread block per bh; writes carry_in for each chunk (fp32)
__global__ void la_scan2(const float* __restrict__ Ebuf, const float* __restrict__ cumg,
                         float* __restrict__ carry) {
  const int bh = blockIdx.x;
  const int b = bh >> 4, h = bh & 15;
  const int lane = threadIdx.x;
  float S0 = 0.f, S1 = 0.f;
  for (int c = 0; c < NCH; c++) {
    size_t idx = ((size_t)bh * NCH + c) * Dd + lane * 2;
    float2 s; s.x = S0; s.y = S1;
    *(float2*)&carry[idx] = s;                   // carry INTO chunk c
    float2 E = *(const float2*)&Ebuf[idx];
    float P = cumg[((size_t)b * Tt + c * CHK + CHK - 1) * Hh + h];  // total chunk gamma
    S0 = fmaf(P, S0, E.x);
    S1 = fmaf(P, S1, E.y);
  }
}

// ---------------- post: mem=local+cumg*carry; LN(mem)*q -> GN -> *sig(og) --
__global__ void la_post(const u16* mem, const u16* q, const u16* ogp,
                        const float* __restrict__ cumg, const float* __restrict__ carry,
                        const float* __restrict__ mng, const float* __restrict__ mnb,
                        const float* __restrict__ gng, const float* __restrict__ gnb,
                        const float* __restrict__ bog, u16* outb) {
  const int wave = threadIdx.x >> 6, lane = threadIdx.x & 63;
  const int p = blockIdx.x * 4 + wave;
  const int row = p >> 4, h = p & 15;
  const int b = row >> 12, t = row & (Tt - 1), ch = t >> 6;  // chunk of 64
  const int d0 = lane * 2;
  const size_t base = (size_t)row * Cc + h * Dd + d0;
  uint32_t um = *(const uint32_t*)(mem + base);
  uint32_t uq = *(const uint32_t*)(q + base);
  uint32_t uo = *(const uint32_t*)(ogp + base);
  float cg = cumg[p];                                        // layout row*Hh+h == p
  float2 cr = *(const float2*)&carry[(((size_t)(b * Hh + h)) * NCH + ch) * Dd + d0];
  float m0 = fmaf(cg, cr.x, bf2f((u16)um));
  float m1 = fmaf(cg, cr.y, bf2f((u16)(um >> 16)));
  float q0 = bf2f((u16)uq), q1 = bf2f((u16)(uq >> 16));
  float g0 = bf2f((u16)uo), g1 = bf2f((u16)(uo >> 16));
  float s1 = wred(m0 + m1);
  float s2 = wred(m0*m0 + m1*m1);
  float mu = s1 * (1.f / Dd);
  float var = s2 * (1.f / Dd) - mu * mu;
  float rs = rsqrtf(var + EPSf);
  int c0 = h * Dd + d0;
  float mo0 = (m0 - mu) * rs * mng[d0]     + mnb[d0];
  float mo1 = (m1 - mu) * rs * mng[d0 + 1] + mnb[d0 + 1];
  float o0 = mo0 * q0, o1 = mo1 * q1;
  float t1 = wred(o0 + o1);
  float t2 = wred(o0*o0 + o1*o1);
  float mu2 = t1 * (1.f / Dd);
  float var2 = t2 * (1.f / Dd) - mu2 * mu2;
  float rs2 = rsqrtf(var2 + EPSf);
  float y0 = (o0 - mu2) * rs2 * gng[c0]     + gnb[c0];
  float y1 = (o1 - mu2) * rs2 * gng[c0 + 1] + gnb[c0 + 1];
  y0 *= sig_(g0 + bog[c0]);
  y1 *= sig_(g1 + bog[c0 + 1]);
  *(uint32_t*)(outb + base) = (uint32_t)f2bf(y0) | ((uint32_t)f2bf(y1) << 16);
}

// ---------------- GEMM (m97 structure): C = A[M,K] @ W[N,K]^T --------------
// 128x128 tile, BK=32, unpadded LDS (rows of 64B), global_load_lds width=16
template <int OUT_BF16>
__global__ __launch_bounds__(256)
void la_gemm(const u16* __restrict__ A, const u16* __restrict__ W,
             void* __restrict__ Co, int M, int N, int K) {
  __shared__ u16 As[128 * 32];   // 8 KB, row stride 32 elems (64 B) — NO padding
  __shared__ u16 Bs[128 * 32];
  const int tid = threadIdx.x;
  const int lane = tid & 63;
  const int wave = tid >> 6;
  const int bm = blockIdx.x * 128;
  const int bn = blockIdx.y * 128;
  const int wm = (wave >> 1) * 64;       // 2x2 wave grid, each 64x64
  const int wn = (wave & 1) * 64;
  const int fm = lane & 15;
  const int fko = (lane >> 4) * 8;

  // staging: wave w call j covers LDS bytes (w*2+j)*1024 .. +1024
  // lane i -> row w*32 + j*16 + (i>>2), k-elems (i&3)*8
  const int sr = wave * 32 + (lane >> 2);
  const int sk = (lane & 3) * 8;
  const u16* Ag = A + (size_t)(bm + sr) * K + sk;
  const u16* Wg = W + (size_t)(bn + sr) * K + sk;
  u16* lA = As + wave * 1024;            // elems (2048 B per wave)
  u16* lB = Bs + wave * 1024;

  f32x4 acc[4][4] = {};

  for (int k0 = 0; k0 < K; k0 += 32) {
    glds16(Ag + k0,          lA);
    glds16(Ag + k0 + 16 * K, lA + 512);
    glds16(Wg + k0,          lB);
    glds16(Wg + k0 + 16 * K, lB + 512);
    __syncthreads();                     // drains vmcnt -> LDS tiles ready
    bf16x8 af[4], bfr[4];
#pragma unroll
    for (int i = 0; i < 4; i++)
      af[i] = *(const bf16x8*)&As[(wm + i * 16 + fm) * 32 + fko];
#pragma unroll
    for (int j = 0; j < 4; j++)
      bfr[j] = *(const bf16x8*)&Bs[(wn + j * 16 + fm) * 32 + fko];
#pragma unroll
    for (int i = 0; i < 4; i++)
#pragma unroll
      for (int j = 0; j < 4; j++)
        acc[i][j] = __builtin_amdgcn_mfma_f32_16x16x32_bf16(af[i], bfr[j], acc[i][j], 0, 0, 0);
    __syncthreads();                     // reads done before next staging
  }

  // C/D layout: row = (lane>>4)*4 + r, col = lane&15
  const int cr = (lane >> 4) * 4;
  const int cc = lane & 15;
#pragma unroll
  for (int i = 0; i < 4; i++) {
#pragma unroll
    for (int j = 0; j < 4; j++) {
#pragma unroll
      for (int r = 0; r < 4; r++) {
        size_t off = (size_t)(bm + wm + i * 16 + cr + r) * N + (bn + wn + j * 16 + cc);
        if (OUT_BF16) ((u16*)Co)[off] = f2bf(acc[i][j][r]);
        else          ((float*)Co)[off] = acc[i][j][r];
      }
    }
  }
}

// ---------------- launcher -------------------------------------------------
extern "C" void kernel_launch(void* const* d_in, const int* in_sizes, int n_in,
                              void* d_out, int out_size, void* d_ws, size_t ws_size,
                              hipStream_t stream) {
  (void)in_sizes; (void)n_in; (void)out_size; (void)ws_size;
  const float* x    = (const float*)d_in[0];
  const float* Wq   = (const float*)d_in[1];
  const float* Wk   = (const float*)d_in[2];
  const float* Wv   = (const float*)d_in[3];
  const float* Wo   = (const float*)d_in[4];
  const float* cw   = (const float*)d_in[5];
  const float* cb   = (const float*)d_in[6];
  const float* Wig  = (const float*)d_in[7];
  const float* big  = (const float*)d_in[8];
  const float* Wog  = (const float*)d_in[9];
  const float* bog  = (const float*)d_in[10];
  const float* Wgam = (const float*)d_in[11];
  const float* bgam = (const float*)d_in[12];
  const float* vng  = (const float*)d_in[13];
  const float* vnb  = (const float*)d_in[14];
  const float* mng  = (const float*)d_in[15];
  const float* mnb  = (const float*)d_in[16];
  const float* gng  = (const float*)d_in[17];
  const float* gnb  = (const float*)d_in[18];

  char* ws = (char*)d_ws;
  const size_t NB = (size_t)Mm * Cc * 2;          // 33,554,432 B per bf16 buffer
  u16* xbf   = (u16*)(ws + 0 * NB);               // x bf16, later out1 bf16
  u16* xconv = (u16*)(ws + 1 * NB);               // silu(conv) bf16
  u16* preq  = (u16*)(ws + 2 * NB);               // q_pre -> q
  u16* prek  = (u16*)(ws + 3 * NB);               // k_pre -> kv -> local mem
  u16* prev  = (u16*)(ws + 4 * NB);               // v_pre -> og_pre
  u16* preig = (u16*)(ws + 5 * NB);               // ig_pre (dead after la_prep)
  u16* wbf   = (u16*)(ws + 6 * NB);               // one bf16 weight slot (reused)
  float* gam = (float*)(ws + 6 * NB + (size_t)Cc * Cc * 2);  // [Mm][Hh] fp32 -> cumg
  // E and carry live in the dead preig region (needs 2 MB; preig is 32 MB)
  float* Ebuf  = (float*)preig;                            // [32][64][128] fp32
  float* carry = (float*)(preig + 1024 * 1024);            // [32][64][128] fp32

  const int NX  = Mm * Cc;        // 16,777,216
  const int WN4 = Cc * Cc / 4;    // 1,048,576
  dim3 blk(256);
  dim3 ggrid(Mm / 128, Cc / 128); // (64,16)

  la_conv<<<NX / 256, blk, 0, stream>>>(x, cw, cb, xbf, xconv);

  la_cvt<<<WN4 / 256, blk, 0, stream>>>(Wq, wbf, WN4);
  la_gemm<1><<<ggrid, blk, 0, stream>>>(xbf, wbf, (void*)preq, Mm, Cc, Cc);
  la_cvt<<<WN4 / 256, blk, 0, stream>>>(Wk, wbf, WN4);
  la_gemm<1><<<ggrid, blk, 0, stream>>>(xbf, wbf, (void*)prek, Mm, Cc, Cc);
  la_cvt<<<WN4 / 256, blk, 0, stream>>>(Wv, wbf, WN4);
  la_gemm<1><<<ggrid, blk, 0, stream>>>(xbf, wbf, (void*)prev, Mm, Cc, Cc);
  la_cvt<<<WN4 / 256, blk, 0, stream>>>(Wig, wbf, WN4);
  la_gemm<1><<<ggrid, blk, 0, stream>>>(xconv, wbf, (void*)preig, Mm, Cc, Cc);

  la_gamma<<<Mm * Hh / 4, blk, 0, stream>>>(xconv, Wgam, bgam, gam);

  la_prep<<<Mm * Hh / 4, blk, 0, stream>>>(preq, prek, prev, preig,
                                           vng, vnb, big, preq, prek);
  // preig dead from here; Ebuf/carry alias it

  la_cvt<<<WN4 / 256, blk, 0, stream>>>(Wog, wbf, WN4);
  la_gemm<1><<<ggrid, blk, 0, stream>>>(xconv, wbf, (void*)prev, Mm, Cc, Cc);

  la_scan1<<<Bb * Hh * NCH / 4, blk, 0, stream>>>(prek, gam, Ebuf);
  la_scan2<<<Bb * Hh, dim3(64), 0, stream>>>(Ebuf, gam, carry);

  la_post<<<Mm * Hh / 4, blk, 0, stream>>>(prek, preq, prev, gam, carry,
                                           mng, mnb, gng, gnb, bog, xbf);

  la_cvt<<<WN4 / 256, blk, 0, stream>>>(Wo, wbf, WN4);
  la_gemm<0><<<ggrid, blk, 0, stream>>>(xbf, wbf, d_out, Mm, Cc, Cc);
}

// Round 3
// 899.919 us; speedup vs baseline: 1.6753x; 1.1612x over previous
//
#include <hip/hip_runtime.h>
#include <cstdint>
#include <cstddef>

using u16 = unsigned short;
using bf16x8 = __attribute__((ext_vector_type(8))) __bf16;
using f32x4  = __attribute__((ext_vector_type(4))) float;

constexpr int Bb = 2, Tt = 4096, Cc = 2048, Hh = 16, Dd = 128;
constexpr int Mm = Bb * Tt;   // 8192 rows
constexpr int CHK = 64;       // scan chunk length
constexpr int NCH = Tt / CHK; // 64 chunks per (b,h)
constexpr float EPSf = 1e-5f;

__device__ __forceinline__ u16 f2bf(float f) {
  union { float f; uint32_t u; } v; v.f = f;
  return (u16)((v.u + 0x7fffu + ((v.u >> 16) & 1u)) >> 16);  // RNE
}
__device__ __forceinline__ float bf2f(u16 h) {
  union { uint32_t u; float f; } v; v.u = ((uint32_t)h) << 16;
  return v.f;
}
__device__ __forceinline__ float sig_(float z) { return 1.f / (1.f + __expf(-z)); }
__device__ __forceinline__ float wred(float v) {
#pragma unroll
  for (int m = 32; m; m >>= 1) v += __shfl_xor(v, m);
  return v;
}
__device__ __forceinline__ void glds16(const u16* g, u16* l) {
  __builtin_amdgcn_global_load_lds(
      (const __attribute__((address_space(1))) unsigned int*)g,
      (__attribute__((address_space(3))) unsigned int*)l, 16, 0, 0);
}

// ---------------- conv (causal depthwise K=4) + silu + bf16 casts ----------
// float4 over channels: thread handles 4 consecutive c's
__global__ void la_conv(const float* __restrict__ x, const float* __restrict__ cw,
                        const float* __restrict__ cb, u16* __restrict__ xbf,
                        u16* __restrict__ xconv) {
  int i4 = blockIdx.x * 256 + threadIdx.x;         // < Mm*Cc/4
  int c4 = i4 & (Cc / 4 - 1);
  int bt = i4 >> 9;                                // /(Cc/4)
  int t = bt & (Tt - 1);
  const float4* x4 = (const float4*)x;
  float4 xv = x4[i4];
  float4 xm1 = t >= 1 ? x4[i4 - Cc / 4] : make_float4(0, 0, 0, 0);
  float4 xm2 = t >= 2 ? x4[i4 - Cc / 2] : make_float4(0, 0, 0, 0);
  float4 xm3 = t >= 3 ? x4[i4 - 3 * Cc / 4] : make_float4(0, 0, 0, 0);
  ushort4 ob; ushort4 oc;
  const float4* cw4 = (const float4*)cw;
  float vv[4]  = {xv.x, xv.y, xv.z, xv.w};
  float v1[4]  = {xm1.x, xm1.y, xm1.z, xm1.w};
  float v2[4]  = {xm2.x, xm2.y, xm2.z, xm2.w};
  float v3[4]  = {xm3.x, xm3.y, xm3.z, xm3.w};
  u16 rb[4], rc[4];
#pragma unroll
  for (int j = 0; j < 4; j++) {
    int c = c4 * 4 + j;
    float4 w = cw4[c];                             // conv_w[c][0][0..3]
    float acc = cb[c] + w.w * vv[j] + w.z * v1[j] + w.y * v2[j] + w.x * v3[j];
    rb[j] = f2bf(vv[j]);
    rc[j] = f2bf(acc * sig_(acc));
  }
  ob.x = rb[0]; ob.y = rb[1]; ob.z = rb[2]; ob.w = rb[3];
  oc.x = rc[0]; oc.y = rc[1]; oc.z = rc[2]; oc.w = rc[3];
  ((ushort4*)xbf)[i4] = ob;
  ((ushort4*)xconv)[i4] = oc;
}

// ---------------- fp32 -> bf16 convert: 5 weights in one dispatch ----------
__global__ void la_cvt5(const float* w0, const float* w1, const float* w2,
                        const float* w3, const float* w4,
                        u16* o0, u16* o1, u16* o2, u16* o3, u16* o4, int n4each) {
  int i = blockIdx.x * 256 + threadIdx.x;
  int seg = i / n4each;                            // block-uniform (n4each % 256 == 0)
  int off = i - seg * n4each;
  const float* src = seg == 0 ? w0 : seg == 1 ? w1 : seg == 2 ? w2 : seg == 3 ? w3 : w4;
  u16* dst = seg == 0 ? o0 : seg == 1 ? o1 : seg == 2 ? o2 : seg == 3 ? o3 : o4;
  float4 v = ((const float4*)src)[off];
  ushort4 o;
  o.x = f2bf(v.x); o.y = f2bf(v.y); o.z = f2bf(v.z); o.w = f2bf(v.w);
  ((ushort4*)dst)[off] = o;
}

__global__ void la_cvt(const float* __restrict__ in, u16* __restrict__ out, int n4) {
  int i = blockIdx.x * 256 + threadIdx.x;
  if (i < n4) {
    float4 v = ((const float4*)in)[i];
    ushort4 o;
    o.x = f2bf(v.x); o.y = f2bf(v.y); o.z = f2bf(v.z); o.w = f2bf(v.w);
    ((ushort4*)out)[i] = o;
  }
}

// ---------------- gamma = sigmoid(xconv @ Wgam.T + bgam) -------------------
__global__ void la_gamma(const u16* __restrict__ xconv, const float* __restrict__ Wg,
                         const float* __restrict__ bg, float* __restrict__ gam) {
  const int wave = threadIdx.x >> 6, lane = threadIdx.x & 63;
  const int p = blockIdx.x * 4 + wave;             // < Mm*Hh
  const int row = p >> 4, h = p & 15;
  const u16* xr = xconv + (size_t)row * Cc;
  const float* wr = Wg + (size_t)h * Cc;
  float acc = 0.f;
#pragma unroll
  for (int it = 0; it < 4; it++) {
    int k = lane * 8 + it * 512;
    bf16x8 xv = *(const bf16x8*)(xr + k);
    float4 w0 = *(const float4*)(wr + k);
    float4 w1 = *(const float4*)(wr + k + 4);
    acc += (float)xv[0]*w0.x + (float)xv[1]*w0.y + (float)xv[2]*w0.z + (float)xv[3]*w0.w;
    acc += (float)xv[4]*w1.x + (float)xv[5]*w1.y + (float)xv[6]*w1.z + (float)xv[7]*w1.w;
  }
  acc = wred(acc);
  if (lane == 0) gam[p] = sig_(acc + bg[h]);
}

// ---------------- prep: q=l2norm, k=l2norm, v=LN, ig=sigmoid, kv=ig*k*v ----
__global__ void la_prep(const u16* pq, const u16* pk, const u16* pv, const u16* pig,
                        const float* __restrict__ vng, const float* __restrict__ vnb,
                        const float* __restrict__ bigv, u16* qo, u16* kvo) {
  const int wave = threadIdx.x >> 6, lane = threadIdx.x & 63;
  const int p = blockIdx.x * 4 + wave;
  const int row = p >> 4, h = p & 15;
  const int d0 = lane * 2;
  const size_t base = (size_t)row * Cc + h * Dd + d0;
  uint32_t uq = *(const uint32_t*)(pq + base);
  uint32_t uk = *(const uint32_t*)(pk + base);
  uint32_t uv = *(const uint32_t*)(pv + base);
  uint32_t ui = *(const uint32_t*)(pig + base);
  float q0 = bf2f((u16)uq), q1 = bf2f((u16)(uq >> 16));
  float k0 = bf2f((u16)uk), k1 = bf2f((u16)(uk >> 16));
  float v0 = bf2f((u16)uv), v1 = bf2f((u16)(uv >> 16));
  float i0 = bf2f((u16)ui), i1 = bf2f((u16)(ui >> 16));
  float qs = wred(q0*q0 + q1*q1);
  float ks = wred(k0*k0 + k1*k1);
  float s1 = wred(v0 + v1);
  float s2 = wred(v0*v0 + v1*v1);
  float qn = 1.f / fmaxf(sqrtf(qs), 1e-12f);
  float kn = 1.f / fmaxf(sqrtf(ks), 1e-12f);
  float mu = s1 * (1.f / Dd);
  float var = s2 * (1.f / Dd) - mu * mu;
  float rs = rsqrtf(var + EPSf);
  int c0 = h * Dd + d0;
  float vh0 = (v0 - mu) * rs * vng[d0]     + vnb[d0];
  float vh1 = (v1 - mu) * rs * vng[d0 + 1] + vnb[d0 + 1];
  float ig0 = sig_(i0 + bigv[c0]);
  float ig1 = sig_(i1 + bigv[c0 + 1]);
  float kv0 = ig0 * (k0 * kn) * vh0;
  float kv1 = ig1 * (k1 * kn) * vh1;
  *(uint32_t*)(qo + base)  = (uint32_t)f2bf(q0 * qn) | ((uint32_t)f2bf(q1 * qn) << 16);
  *(uint32_t*)(kvo + base) = (uint32_t)f2bf(kv0)     | ((uint32_t)f2bf(kv1) << 16);
}

// ---------------- scan phase 1: local chunk scans --------------------------
__global__ void la_scan1(u16* __restrict__ kv, float* __restrict__ gam,
                         float* __restrict__ Ebuf) {
  const int wave = threadIdx.x >> 6, lane = threadIdx.x & 63;
  const int p = blockIdx.x * 4 + wave;           // < Bb*Hh*NCH
  const int bh = p >> 6, c = p & (NCH - 1);
  const int b = bh >> 4, h = bh & 15;
  const int t0 = c * CHK;
  const size_t rbase = (size_t)b * Tt + t0;      // first global row of chunk
  const size_t base = rbase * Cc + h * Dd + lane * 2;
  float* gp = gam + rbase * Hh + h;
  float m0 = 0.f, m1 = 0.f, cg = 1.f;
#pragma unroll 4
  for (int t = 0; t < CHK; t++) {
    float g = gp[(size_t)t * Hh];
    cg *= g;
    uint32_t u = *(const uint32_t*)(kv + base + (size_t)t * Cc);
    m0 = fmaf(g, m0, bf2f((u16)u));
    m1 = fmaf(g, m1, bf2f((u16)(u >> 16)));
    *(uint32_t*)(kv + base + (size_t)t * Cc) =
        (uint32_t)f2bf(m0) | ((uint32_t)f2bf(m1) << 16);
    if (lane == 0) gp[(size_t)t * Hh] = cg;      // cumgamma from chunk start
  }
  float2 e; e.x = m0; e.y = m1;
  *(float2*)&Ebuf[(size_t)p * Dd + lane * 2] = e;
}

// ---------------- scan phase 2: carry across chunks ------------------------
__global__ void la_scan2(const float* __restrict__ Ebuf, const float* __restrict__ cumg,
                         float* __restrict__ carry) {
  const int bh = blockIdx.x;
  const int b = bh >> 4, h = bh & 15;
  const int lane = threadIdx.x;
  float S0 = 0.f, S1 = 0.f;
  for (int c = 0; c < NCH; c++) {
    size_t idx = ((size_t)bh * NCH + c) * Dd + lane * 2;
    float2 s; s.x = S0; s.y = S1;
    *(float2*)&carry[idx] = s;                   // carry INTO chunk c
    float2 E = *(const float2*)&Ebuf[idx];
    float P = cumg[((size_t)b * Tt + c * CHK + CHK - 1) * Hh + h];
    S0 = fmaf(P, S0, E.x);
    S1 = fmaf(P, S1, E.y);
  }
}

// ---------------- post: mem=local+cumg*carry; LN(mem)*q -> GN -> *sig(og) --
__global__ void la_post(const u16* mem, const u16* q, const u16* ogp,
                        const float* __restrict__ cumg, const float* __restrict__ carry,
                        const float* __restrict__ mng, const float* __restrict__ mnb,
                        const float* __restrict__ gng, const float* __restrict__ gnb,
                        const float* __restrict__ bog, u16* outb) {
  const int wave = threadIdx.x >> 6, lane = threadIdx.x & 63;
  const int p = blockIdx.x * 4 + wave;
  const int row = p >> 4, h = p & 15;
  const int b = row >> 12, t = row & (Tt - 1), ch = t >> 6;
  const int d0 = lane * 2;
  const size_t base = (size_t)row * Cc + h * Dd + d0;
  uint32_t um = *(const uint32_t*)(mem + base);
  uint32_t uq = *(const uint32_t*)(q + base);
  uint32_t uo = *(const uint32_t*)(ogp + base);
  float cg = cumg[p];
  float2 cr = *(const float2*)&carry[(((size_t)(b * Hh + h)) * NCH + ch) * Dd + d0];
  float m0 = fmaf(cg, cr.x, bf2f((u16)um));
  float m1 = fmaf(cg, cr.y, bf2f((u16)(um >> 16)));
  float q0 = bf2f((u16)uq), q1 = bf2f((u16)(uq >> 16));
  float g0 = bf2f((u16)uo), g1 = bf2f((u16)(uo >> 16));
  float s1 = wred(m0 + m1);
  float s2 = wred(m0*m0 + m1*m1);
  float mu = s1 * (1.f / Dd);
  float var = s2 * (1.f / Dd) - mu * mu;
  float rs = rsqrtf(var + EPSf);
  int c0 = h * Dd + d0;
  float mo0 = (m0 - mu) * rs * mng[d0]     + mnb[d0];
  float mo1 = (m1 - mu) * rs * mng[d0 + 1] + mnb[d0 + 1];
  float o0 = mo0 * q0, o1 = mo1 * q1;
  float t1 = wred(o0 + o1);
  float t2 = wred(o0*o0 + o1*o1);
  float mu2 = t1 * (1.f / Dd);
  float var2 = t2 * (1.f / Dd) - mu2 * mu2;
  float rs2 = rsqrtf(var2 + EPSf);
  float y0 = (o0 - mu2) * rs2 * gng[c0]     + gnb[c0];
  float y1 = (o1 - mu2) * rs2 * gng[c0 + 1] + gnb[c0 + 1];
  y0 *= sig_(g0 + bog[c0]);
  y1 *= sig_(g1 + bog[c0 + 1]);
  *(uint32_t*)(outb + base) = (uint32_t)f2bf(y0) | ((uint32_t)f2bf(y1) << 16);
}

// ---------------- GEMM: C = A @ W^T, 128x128 tile, BK=64, swizzled LDS -----
// LDS slot s (16B, 8 elems) of a 128x64 tile: s = r*8 + (q ^ (r&7)),
// q = global k-chunk. Staging (glds lane i -> slot base+i) loads global
// chunk g=(i&7)^(i>>3) so stored chunk index matches; reads use q^(fm&7).
// Per 16-lane quarter the b128 reads cover all 8 4-bank groups exactly 2x
// (2-way is free, m136).  Multi-segment: seg = blockIdx.x>>4 picks W/C.
template <int OUT_BF16>
__global__ __launch_bounds__(256)
void la_gemm(const u16* __restrict__ A,
             const u16* __restrict__ W0, const u16* __restrict__ W1,
             const u16* __restrict__ W2,
             void* __restrict__ C0, void* __restrict__ C1, void* __restrict__ C2,
             int K) {
  __shared__ u16 As[128 * 64];   // 16 KB
  __shared__ u16 Bs[128 * 64];
  const int tid = threadIdx.x;
  const int lane = tid & 63;
  const int wave = tid >> 6;
  const int seg = blockIdx.x >> 4;
  const int bn = (blockIdx.x & 15) * 128;
  const int bm = blockIdx.y * 128;
  const u16* W = seg == 0 ? W0 : (seg == 1 ? W1 : W2);
  void* Co = seg == 0 ? C0 : (seg == 1 ? C1 : C2);
  const int wm = (wave >> 1) * 64;
  const int wn = (wave & 1) * 64;
  const int fm = lane & 15;

  // staging: call j covers rows wave*32 + j*8 + (lane>>3), chunk (lane&7)^(lane>>3)
  const int srow = wave * 32 + (lane >> 3);
  const int sg   = ((lane & 7) ^ (lane >> 3)) * 8;
  const u16* Ag = A + (size_t)(bm + srow) * K + sg;
  const u16* Wg = W + (size_t)(bn + srow) * K + sg;
  u16* lA = As + wave * 2048;          // wave-uniform LDS base (elems)
  u16* lB = Bs + wave * 2048;

  f32x4 acc[4][4] = {};

  for (int k0 = 0; k0 < K; k0 += 64) {
#pragma unroll
    for (int j = 0; j < 4; j++) {
      glds16(Ag + k0 + j * 8 * K, lA + j * 512);
      glds16(Wg + k0 + j * 8 * K, lB + j * 512);
    }
    __syncthreads();
#pragma unroll
    for (int kk = 0; kk < 2; kk++) {
      const int qs = (((lane >> 4) + kk * 4) ^ (fm & 7)) * 8;
      bf16x8 af[4], bfr[4];
#pragma unroll
      for (int i = 0; i < 4; i++)
        af[i] = *(const bf16x8*)&As[(wm + i * 16 + fm) * 64 + qs];
#pragma unroll
      for (int j = 0; j < 4; j++)
        bfr[j] = *(const bf16x8*)&Bs[(wn + j * 16 + fm) * 64 + qs];
#pragma unroll
      for (int i = 0; i < 4; i++)
#pragma unroll
        for (int j = 0; j < 4; j++)
          acc[i][j] = __builtin_amdgcn_mfma_f32_16x16x32_bf16(af[i], bfr[j], acc[i][j], 0, 0, 0);
    }
    __syncthreads();
  }

  // C/D layout: row = (lane>>4)*4 + r, col = lane&15 ; C row stride = 2048
  const int cr = (lane >> 4) * 4;
  const int cc = lane & 15;
#pragma unroll
  for (int i = 0; i < 4; i++) {
#pragma unroll
    for (int j = 0; j < 4; j++) {
#pragma unroll
      for (int r = 0; r < 4; r++) {
        size_t off = (size_t)(bm + wm + i * 16 + cr + r) * Cc + (bn + wn + j * 16 + cc);
        if (OUT_BF16) ((u16*)Co)[off] = f2bf(acc[i][j][r]);
        else          ((float*)Co)[off] = acc[i][j][r];
      }
    }
  }
}

// ---------------- launcher -------------------------------------------------
extern "C" void kernel_launch(void* const* d_in, const int* in_sizes, int n_in,
                              void* d_out, int out_size, void* d_ws, size_t ws_size,
                              hipStream_t stream) {
  (void)in_sizes; (void)n_in; (void)out_size; (void)ws_size;
  const float* x    = (const float*)d_in[0];
  const float* Wq   = (const float*)d_in[1];
  const float* Wk   = (const float*)d_in[2];
  const float* Wv   = (const float*)d_in[3];
  const float* Wo   = (const float*)d_in[4];
  const float* cw   = (const float*)d_in[5];
  const float* cb   = (const float*)d_in[6];
  const float* Wig  = (const float*)d_in[7];
  const float* big  = (const float*)d_in[8];
  const float* Wog  = (const float*)d_in[9];
  const float* bog  = (const float*)d_in[10];
  const float* Wgam = (const float*)d_in[11];
  const float* bgam = (const float*)d_in[12];
  const float* vng  = (const float*)d_in[13];
  const float* vnb  = (const float*)d_in[14];
  const float* mng  = (const float*)d_in[15];
  const float* mnb  = (const float*)d_in[16];
  const float* gng  = (const float*)d_in[17];
  const float* gnb  = (const float*)d_in[18];

  char* ws = (char*)d_ws;
  const size_t NB = (size_t)Mm * Cc * 2;          // 32 MB per bf16 activation buf
  u16* xbf   = (u16*)(ws + 0 * NB);               // x bf16 -> ig -> post out
  u16* xconv = (u16*)(ws + 1 * NB);               // silu(conv) bf16
  u16* preq  = (u16*)(ws + 2 * NB);               // q_pre -> q
  u16* prek  = (u16*)(ws + 3 * NB);               // k_pre -> kv -> local mem
  u16* prev  = (u16*)(ws + 4 * NB);               // v_pre -> og_pre
  u16* preig = (u16*)(ws + 5 * NB);               // Wk,Wv,Wig,Wog bf16 -> E/carry
  u16* wbf   = (u16*)(ws + 6 * NB);               // Wq bf16 -> Wo bf16 (8 MB)
  float* gam = (float*)(ws + 6 * NB + (size_t)Cc * Cc * 2);  // [Mm][Hh] -> cumg
  const size_t WE = (size_t)Cc * Cc;              // 4,194,304 elems per weight
  u16* wk_bf  = preig;
  u16* wv_bf  = preig + WE;
  u16* wig_bf = preig + 2 * WE;
  u16* wog_bf = preig + 3 * WE;
  float* Ebuf  = (float*)preig;                   // 1 MB (after weights dead)
  float* carry = (float*)(preig + 1024 * 1024);   // 1 MB at +2 MB

  const int WN4 = Cc * Cc / 4;    // 1,048,576 float4 per weight
  dim3 blk(256);

  la_conv<<<Mm * Cc / 4 / 256, blk, 0, stream>>>(x, cw, cb, xbf, xconv);

  la_cvt5<<<5 * WN4 / 256, blk, 0, stream>>>(Wq, Wk, Wv, Wig, Wog,
                                             wbf, wk_bf, wv_bf, wig_bf, wog_bf, WN4);

  // merged QKV: 3 segments, N = 3*2048
  la_gemm<1><<<dim3(48, Mm / 128), blk, 0, stream>>>(
      xbf, wbf, wk_bf, wv_bf, (void*)preq, (void*)prek, (void*)prev, Cc);

  // ig GEMM: output into xbf (x bf16 dead after QKV)
  la_gemm<1><<<dim3(16, Mm / 128), blk, 0, stream>>>(
      xconv, wig_bf, wig_bf, wig_bf, (void*)xbf, (void*)xbf, (void*)xbf, Cc);

  la_gamma<<<Mm * Hh / 4, blk, 0, stream>>>(xconv, Wgam, bgam, gam);

  la_prep<<<Mm * Hh / 4, blk, 0, stream>>>(preq, prek, prev, xbf,
                                           vng, vnb, big, preq, prek);

  // og GEMM: prev dead after prep
  la_gemm<1><<<dim3(16, Mm / 128), blk, 0, stream>>>(
      xconv, wog_bf, wog_bf, wog_bf, (void*)prev, (void*)prev, (void*)prev, Cc);

  la_scan1<<<Bb * Hh * NCH / 4, blk, 0, stream>>>(prek, gam, Ebuf);
  la_scan2<<<Bb * Hh, dim3(64), 0, stream>>>(Ebuf, gam, carry);

  la_post<<<Mm * Hh / 4, blk, 0, stream>>>(prek, preq, prev, gam, carry,
                                           mng, mnb, gng, gnb, bog, xbf);

  la_cvt<<<WN4 / 256, blk, 0, stream>>>(Wo, wbf, WN4);
  la_gemm<0><<<dim3(16, Mm / 128), blk, 0, stream>>>(
      xbf, wbf, wbf, wbf, d_out, d_out, d_out, Cc);
}

// Round 4
// 835.473 us; speedup vs baseline: 1.8045x; 1.0771x over previous
//
#include <hip/hip_runtime.h>
#include <cstdint>
#include <cstddef>

using u16 = unsigned short;
using bf16x8 = __attribute__((ext_vector_type(8))) __bf16;
using f32x4  = __attribute__((ext_vector_type(4))) float;

constexpr int Bb = 2, Tt = 4096, Cc = 2048, Hh = 16, Dd = 128;
constexpr int Mm = Bb * Tt;   // 8192 rows
constexpr int CHK = 32;       // scan chunk length
constexpr int NCH = Tt / CHK; // 128 chunks per (b,h)
constexpr float EPSf = 1e-5f;

__device__ __forceinline__ u16 f2bf(float f) {
  union { float f; uint32_t u; } v; v.f = f;
  return (u16)((v.u + 0x7fffu + ((v.u >> 16) & 1u)) >> 16);  // RNE
}
__device__ __forceinline__ float bf2f(u16 h) {
  union { uint32_t u; float f; } v; v.u = ((uint32_t)h) << 16;
  return v.f;
}
__device__ __forceinline__ float sig_(float z) { return 1.f / (1.f + __expf(-z)); }
__device__ __forceinline__ float wred(float v) {
#pragma unroll
  for (int m = 32; m; m >>= 1) v += __shfl_xor(v, m);
  return v;
}
__device__ __forceinline__ void glds16(const u16* g, u16* l) {
  __builtin_amdgcn_global_load_lds(
      (const __attribute__((address_space(1))) unsigned int*)g,
      (__attribute__((address_space(3))) unsigned int*)l, 16, 0, 0);
}

// ---------------- conv (causal depthwise K=4) + silu + bf16 casts ----------
__global__ void la_conv(const float* __restrict__ x, const float* __restrict__ cw,
                        const float* __restrict__ cb, u16* __restrict__ xbf,
                        u16* __restrict__ xconv) {
  int i4 = blockIdx.x * 256 + threadIdx.x;         // < Mm*Cc/4
  int c4 = i4 & (Cc / 4 - 1);
  int bt = i4 >> 9;                                // /(Cc/4)
  int t = bt & (Tt - 1);
  const float4* x4 = (const float4*)x;
  float4 xv = x4[i4];
  float4 xm1 = t >= 1 ? x4[i4 - Cc / 4] : make_float4(0, 0, 0, 0);
  float4 xm2 = t >= 2 ? x4[i4 - Cc / 2] : make_float4(0, 0, 0, 0);
  float4 xm3 = t >= 3 ? x4[i4 - 3 * Cc / 4] : make_float4(0, 0, 0, 0);
  ushort4 ob; ushort4 oc;
  const float4* cw4 = (const float4*)cw;
  float vv[4]  = {xv.x, xv.y, xv.z, xv.w};
  float v1[4]  = {xm1.x, xm1.y, xm1.z, xm1.w};
  float v2[4]  = {xm2.x, xm2.y, xm2.z, xm2.w};
  float v3[4]  = {xm3.x, xm3.y, xm3.z, xm3.w};
  u16 rb[4], rc[4];
#pragma unroll
  for (int j = 0; j < 4; j++) {
    int c = c4 * 4 + j;
    float4 w = cw4[c];
    float acc = cb[c] + w.w * vv[j] + w.z * v1[j] + w.y * v2[j] + w.x * v3[j];
    rb[j] = f2bf(vv[j]);
    rc[j] = f2bf(acc * sig_(acc));
  }
  ob.x = rb[0]; ob.y = rb[1]; ob.z = rb[2]; ob.w = rb[3];
  oc.x = rc[0]; oc.y = rc[1]; oc.z = rc[2]; oc.w = rc[3];
  ((ushort4*)xbf)[i4] = ob;
  ((ushort4*)xconv)[i4] = oc;
}

// ---------------- fp32 -> bf16 convert: 5 weights in one dispatch ----------
__global__ void la_cvt5(const float* w0, const float* w1, const float* w2,
                        const float* w3, const float* w4,
                        u16* o0, u16* o1, u16* o2, u16* o3, u16* o4, int n4each) {
  int i = blockIdx.x * 256 + threadIdx.x;
  int seg = i / n4each;                            // block-uniform
  int off = i - seg * n4each;
  const float* src = seg == 0 ? w0 : seg == 1 ? w1 : seg == 2 ? w2 : seg == 3 ? w3 : w4;
  u16* dst = seg == 0 ? o0 : seg == 1 ? o1 : seg == 2 ? o2 : seg == 3 ? o3 : o4;
  float4 v = ((const float4*)src)[off];
  ushort4 o;
  o.x = f2bf(v.x); o.y = f2bf(v.y); o.z = f2bf(v.z); o.w = f2bf(v.w);
  ((ushort4*)dst)[off] = o;
}

__global__ void la_cvt(const float* __restrict__ in, u16* __restrict__ out, int n4) {
  int i = blockIdx.x * 256 + threadIdx.x;
  if (i < n4) {
    float4 v = ((const float4*)in)[i];
    ushort4 o;
    o.x = f2bf(v.x); o.y = f2bf(v.y); o.z = f2bf(v.z); o.w = f2bf(v.w);
    ((ushort4*)out)[i] = o;
  }
}

// ---------------- gamma = sigmoid(xconv @ Wgam.T + bgam) -------------------
// block = 256 threads handles 16 rows x 16 heads; Wgam staged once in LDS (bf16)
__global__ __launch_bounds__(256) void la_gamma(
    const u16* __restrict__ xconv, const float* __restrict__ Wg,
    const float* __restrict__ bg, float* __restrict__ gam) {
  __shared__ u16 wlds[Hh * Cc];                    // 64 KB
  for (int i = threadIdx.x; i < Hh * Cc / 4; i += 256) {
    float4 v = ((const float4*)Wg)[i];
    ushort4 o;
    o.x = f2bf(v.x); o.y = f2bf(v.y); o.z = f2bf(v.z); o.w = f2bf(v.w);
    ((ushort4*)wlds)[i] = o;
  }
  __syncthreads();
  const int wave = threadIdx.x >> 6, lane = threadIdx.x & 63;
  const int row0 = blockIdx.x * 16 + wave * 4;
#pragma unroll
  for (int r = 0; r < 4; r++) {
    const int row = row0 + r;
    const u16* xr = xconv + (size_t)row * Cc + lane * 8;
    bf16x8 xv[4];
#pragma unroll
    for (int it = 0; it < 4; it++) xv[it] = *(const bf16x8*)(xr + it * 512);
#pragma unroll
    for (int h = 0; h < 16; h++) {
      const u16* wr = wlds + h * Cc + lane * 8;
      float acc = 0.f;
#pragma unroll
      for (int it = 0; it < 4; it++) {
        bf16x8 wv = *(const bf16x8*)(wr + it * 512);
#pragma unroll
        for (int e = 0; e < 8; e++) acc += (float)xv[it][e] * (float)wv[e];
      }
      acc = wred(acc);
      if (lane == 0) gam[row * Hh + h] = sig_(acc + bg[h]);
    }
  }
}

// ---------------- prep: q=l2norm, k=l2norm, v=LN, ig=sigmoid, kv=ig*k*v ----
__global__ void la_prep(const u16* pq, const u16* pk, const u16* pv, const u16* pig,
                        const float* __restrict__ vng, const float* __restrict__ vnb,
                        const float* __restrict__ bigv, u16* qo, u16* kvo) {
  const int wave = threadIdx.x >> 6, lane = threadIdx.x & 63;
  const int p = blockIdx.x * 4 + wave;
  const int row = p >> 4, h = p & 15;
  const int d0 = lane * 2;
  const size_t base = (size_t)row * Cc + h * Dd + d0;
  uint32_t uq = *(const uint32_t*)(pq + base);
  uint32_t uk = *(const uint32_t*)(pk + base);
  uint32_t uv = *(const uint32_t*)(pv + base);
  uint32_t ui = *(const uint32_t*)(pig + base);
  float q0 = bf2f((u16)uq), q1 = bf2f((u16)(uq >> 16));
  float k0 = bf2f((u16)uk), k1 = bf2f((u16)(uk >> 16));
  float v0 = bf2f((u16)uv), v1 = bf2f((u16)(uv >> 16));
  float i0 = bf2f((u16)ui), i1 = bf2f((u16)(ui >> 16));
  float qs = wred(q0*q0 + q1*q1);
  float ks = wred(k0*k0 + k1*k1);
  float s1 = wred(v0 + v1);
  float s2 = wred(v0*v0 + v1*v1);
  float qn = 1.f / fmaxf(sqrtf(qs), 1e-12f);
  float kn = 1.f / fmaxf(sqrtf(ks), 1e-12f);
  float mu = s1 * (1.f / Dd);
  float var = s2 * (1.f / Dd) - mu * mu;
  float rs = rsqrtf(var + EPSf);
  int c0 = h * Dd + d0;
  float vh0 = (v0 - mu) * rs * vng[d0]     + vnb[d0];
  float vh1 = (v1 - mu) * rs * vng[d0 + 1] + vnb[d0 + 1];
  float ig0 = sig_(i0 + bigv[c0]);
  float ig1 = sig_(i1 + bigv[c0 + 1]);
  float kv0 = ig0 * (k0 * kn) * vh0;
  float kv1 = ig1 * (k1 * kn) * vh1;
  *(uint32_t*)(qo + base)  = (uint32_t)f2bf(q0 * qn) | ((uint32_t)f2bf(q1 * qn) << 16);
  *(uint32_t*)(kvo + base) = (uint32_t)f2bf(kv0)     | ((uint32_t)f2bf(kv1) << 16);
}

// ---------------- scan phase 1: local chunk scans (CHK=32) -----------------
__global__ void la_scan1(u16* __restrict__ kv, float* __restrict__ gam,
                         float* __restrict__ Ebuf) {
  const int wave = threadIdx.x >> 6, lane = threadIdx.x & 63;
  const int p = blockIdx.x * 4 + wave;           // < Bb*Hh*NCH
  const int bh = p >> 7, c = p & (NCH - 1);
  const int b = bh >> 4, h = bh & 15;
  const int t0 = c * CHK;
  const size_t rbase = (size_t)b * Tt + t0;
  const size_t base = rbase * Cc + h * Dd + lane * 2;
  float* gp = gam + rbase * Hh + h;
  float m0 = 0.f, m1 = 0.f, cg = 1.f;
#pragma unroll 4
  for (int t = 0; t < CHK; t++) {
    float g = gp[(size_t)t * Hh];
    cg *= g;
    uint32_t u = *(const uint32_t*)(kv + base + (size_t)t * Cc);
    m0 = fmaf(g, m0, bf2f((u16)u));
    m1 = fmaf(g, m1, bf2f((u16)(u >> 16)));
    *(uint32_t*)(kv + base + (size_t)t * Cc) =
        (uint32_t)f2bf(m0) | ((uint32_t)f2bf(m1) << 16);
    if (lane == 0) gp[(size_t)t * Hh] = cg;      // cumgamma from chunk start
  }
  float2 e; e.x = m0; e.y = m1;
  *(float2*)&Ebuf[(size_t)p * Dd + lane * 2] = e;
}

// ---------------- scan phase 2: carry across chunks ------------------------
__global__ void la_scan2(const float* __restrict__ Ebuf, const float* __restrict__ cumg,
                         float* __restrict__ carry) {
  const int bh = blockIdx.x;
  const int b = bh >> 4, h = bh & 15;
  const int lane = threadIdx.x;
  float S0 = 0.f, S1 = 0.f;
  for (int c = 0; c < NCH; c++) {
    size_t idx = ((size_t)bh * NCH + c) * Dd + lane * 2;
    float2 s; s.x = S0; s.y = S1;
    *(float2*)&carry[idx] = s;                   // carry INTO chunk c
    float2 E = *(const float2*)&Ebuf[idx];
    float P = cumg[((size_t)b * Tt + c * CHK + CHK - 1) * Hh + h];
    S0 = fmaf(P, S0, E.x);
    S1 = fmaf(P, S1, E.y);
  }
}

// ---------------- post: mem=local+cumg*carry; LN(mem)*q -> GN -> *sig(og) --
__global__ void la_post(const u16* mem, const u16* q, const u16* ogp,
                        const float* __restrict__ cumg, const float* __restrict__ carry,
                        const float* __restrict__ mng, const float* __restrict__ mnb,
                        const float* __restrict__ gng, const float* __restrict__ gnb,
                        const float* __restrict__ bog, u16* outb) {
  const int wave = threadIdx.x >> 6, lane = threadIdx.x & 63;
  const int p = blockIdx.x * 4 + wave;
  const int row = p >> 4, h = p & 15;
  const int b = row >> 12, t = row & (Tt - 1), ch = t >> 5;  // CHK=32
  const int d0 = lane * 2;
  const size_t base = (size_t)row * Cc + h * Dd + d0;
  uint32_t um = *(const uint32_t*)(mem + base);
  uint32_t uq = *(const uint32_t*)(q + base);
  uint32_t uo = *(const uint32_t*)(ogp + base);
  float cg = cumg[p];
  float2 cr = *(const float2*)&carry[(((size_t)(b * Hh + h)) * NCH + ch) * Dd + d0];
  float m0 = fmaf(cg, cr.x, bf2f((u16)um));
  float m1 = fmaf(cg, cr.y, bf2f((u16)(um >> 16)));
  float q0 = bf2f((u16)uq), q1 = bf2f((u16)(uq >> 16));
  float g0 = bf2f((u16)uo), g1 = bf2f((u16)(uo >> 16));
  float s1 = wred(m0 + m1);
  float s2 = wred(m0*m0 + m1*m1);
  float mu = s1 * (1.f / Dd);
  float var = s2 * (1.f / Dd) - mu * mu;
  float rs = rsqrtf(var + EPSf);
  int c0 = h * Dd + d0;
  float mo0 = (m0 - mu) * rs * mng[d0]     + mnb[d0];
  float mo1 = (m1 - mu) * rs * mng[d0 + 1] + mnb[d0 + 1];
  float o0 = mo0 * q0, o1 = mo1 * q1;
  float t1 = wred(o0 + o1);
  float t2 = wred(o0*o0 + o1*o1);
  float mu2 = t1 * (1.f / Dd);
  float var2 = t2 * (1.f / Dd) - mu2 * mu2;
  float rs2 = rsqrtf(var2 + EPSf);
  float y0 = (o0 - mu2) * rs2 * gng[c0]     + gnb[c0];
  float y1 = (o1 - mu2) * rs2 * gng[c0 + 1] + gnb[c0 + 1];
  y0 *= sig_(g0 + bog[c0]);
  y1 *= sig_(g1 + bog[c0 + 1]);
  *(uint32_t*)(outb + base) = (uint32_t)f2bf(y0) | ((uint32_t)f2bf(y1) << 16);
}

// ---------------- GEMM: C = A @ W^T, 128x128 tile, BK=64, swizzled LDS -----
template <int OUT_BF16>
__global__ __launch_bounds__(256)
void la_gemm(const u16* __restrict__ A,
             const u16* __restrict__ W0, const u16* __restrict__ W1,
             const u16* __restrict__ W2,
             void* __restrict__ C0, void* __restrict__ C1, void* __restrict__ C2,
             int K) {
  __shared__ u16 As[128 * 64];   // 16 KB
  __shared__ u16 Bs[128 * 64];
  const int tid = threadIdx.x;
  const int lane = tid & 63;
  const int wave = tid >> 6;
  const int seg = blockIdx.x >> 4;
  const int bn = (blockIdx.x & 15) * 128;
  const int bm = blockIdx.y * 128;
  const u16* W = seg == 0 ? W0 : (seg == 1 ? W1 : W2);
  void* Co = seg == 0 ? C0 : (seg == 1 ? C1 : C2);
  const int wm = (wave >> 1) * 64;
  const int wn = (wave & 1) * 64;
  const int fm = lane & 15;

  const int srow = wave * 32 + (lane >> 3);
  const int sg   = ((lane & 7) ^ (lane >> 3)) * 8;
  const u16* Ag = A + (size_t)(bm + srow) * K + sg;
  const u16* Wg = W + (size_t)(bn + srow) * K + sg;
  u16* lA = As + wave * 2048;
  u16* lB = Bs + wave * 2048;

  f32x4 acc[4][4] = {};

  for (int k0 = 0; k0 < K; k0 += 64) {
#pragma unroll
    for (int j = 0; j < 4; j++) {
      glds16(Ag + k0 + j * 8 * K, lA + j * 512);
      glds16(Wg + k0 + j * 8 * K, lB + j * 512);
    }
    __syncthreads();
#pragma unroll
    for (int kk = 0; kk < 2; kk++) {
      const int qs = (((lane >> 4) + kk * 4) ^ (fm & 7)) * 8;
      bf16x8 af[4], bfr[4];
#pragma unroll
      for (int i = 0; i < 4; i++)
        af[i] = *(const bf16x8*)&As[(wm + i * 16 + fm) * 64 + qs];
#pragma unroll
      for (int j = 0; j < 4; j++)
        bfr[j] = *(const bf16x8*)&Bs[(wn + j * 16 + fm) * 64 + qs];
#pragma unroll
      for (int i = 0; i < 4; i++)
#pragma unroll
        for (int j = 0; j < 4; j++)
          acc[i][j] = __builtin_amdgcn_mfma_f32_16x16x32_bf16(af[i], bfr[j], acc[i][j], 0, 0, 0);
    }
    __syncthreads();
  }

  const int cr = (lane >> 4) * 4;
  const int cc = lane & 15;
#pragma unroll
  for (int i = 0; i < 4; i++) {
#pragma unroll
    for (int j = 0; j < 4; j++) {
#pragma unroll
      for (int r = 0; r < 4; r++) {
        size_t off = (size_t)(bm + wm + i * 16 + cr + r) * Cc + (bn + wn + j * 16 + cc);
        if (OUT_BF16) ((u16*)Co)[off] = f2bf(acc[i][j][r]);
        else          ((float*)Co)[off] = acc[i][j][r];
      }
    }
  }
}

// ---------------- launcher -------------------------------------------------
extern "C" void kernel_launch(void* const* d_in, const int* in_sizes, int n_in,
                              void* d_out, int out_size, void* d_ws, size_t ws_size,
                              hipStream_t stream) {
  (void)in_sizes; (void)n_in; (void)out_size; (void)ws_size;
  const float* x    = (const float*)d_in[0];
  const float* Wq   = (const float*)d_in[1];
  const float* Wk   = (const float*)d_in[2];
  const float* Wv   = (const float*)d_in[3];
  const float* Wo   = (const float*)d_in[4];
  const float* cw   = (const float*)d_in[5];
  const float* cb   = (const float*)d_in[6];
  const float* Wig  = (const float*)d_in[7];
  const float* big  = (const float*)d_in[8];
  const float* Wog  = (const float*)d_in[9];
  const float* bog  = (const float*)d_in[10];
  const float* Wgam = (const float*)d_in[11];
  const float* bgam = (const float*)d_in[12];
  const float* vng  = (const float*)d_in[13];
  const float* vnb  = (const float*)d_in[14];
  const float* mng  = (const float*)d_in[15];
  const float* mnb  = (const float*)d_in[16];
  const float* gng  = (const float*)d_in[17];
  const float* gnb  = (const float*)d_in[18];

  char* ws = (char*)d_ws;
  const size_t NB = (size_t)Mm * Cc * 2;          // 32 MB per bf16 activation buf
  u16* xbf   = (u16*)(ws + 0 * NB);               // x bf16 -> ig -> post out
  u16* xconv = (u16*)(ws + 1 * NB);               // silu(conv) bf16
  u16* preq  = (u16*)(ws + 2 * NB);               // q_pre -> q
  u16* prek  = (u16*)(ws + 3 * NB);               // k_pre -> kv -> local mem
  u16* prev  = (u16*)(ws + 4 * NB);               // v_pre (dead after prep)
  u16* preig = (u16*)(ws + 5 * NB);               // Wk,Wv,Wig,Wog bf16 -> E/carry
  u16* wbf   = (u16*)(ws + 6 * NB);               // Wq bf16 -> Wo bf16 (8 MB)
  float* gam = (float*)(ws + 6 * NB + (size_t)Cc * Cc * 2);  // [Mm][Hh] -> cumg
  const size_t WE = (size_t)Cc * Cc;
  u16* wk_bf  = preig;
  u16* wv_bf  = preig + WE;
  u16* wig_bf = preig + 2 * WE;
  u16* wog_bf = preig + 3 * WE;
  float* Ebuf  = (float*)preig;                   // 2 MB (weights dead by scan1)
  float* carry = (float*)(preig + 1024 * 1024);   // 2 MB at +2 MB
  u16* ogscr = (u16*)d_out;                       // og_pre bf16 scratch (32 of 64 MB)

  const int WN4 = Cc * Cc / 4;
  dim3 blk(256);

  la_conv<<<Mm * Cc / 4 / 256, blk, 0, stream>>>(x, cw, cb, xbf, xconv);

  la_cvt5<<<5 * WN4 / 256, blk, 0, stream>>>(Wq, Wk, Wv, Wig, Wog,
                                             wbf, wk_bf, wv_bf, wig_bf, wog_bf, WN4);

  // merged QKV: 3 segments, N = 3*2048
  la_gemm<1><<<dim3(48, Mm / 128), blk, 0, stream>>>(
      xbf, wbf, wk_bf, wv_bf, (void*)preq, (void*)prek, (void*)prev, Cc);

  // Wq slot dead -> convert Wo early
  la_cvt<<<WN4 / 256, blk, 0, stream>>>(Wo, wbf, WN4);

  // merged ig+og: A = xconv; ig -> xbf (dead), og -> d_out scratch
  la_gemm<1><<<dim3(32, Mm / 128), blk, 0, stream>>>(
      xconv, wig_bf, wog_bf, wog_bf, (void*)xbf, (void*)ogscr, (void*)ogscr, Cc);

  la_gamma<<<Mm / 16, blk, 0, stream>>>(xconv, Wgam, bgam, gam);

  la_prep<<<Mm * Hh / 4, blk, 0, stream>>>(preq, prek, prev, xbf,
                                           vng, vnb, big, preq, prek);

  la_scan1<<<Bb * Hh * NCH / 4, blk, 0, stream>>>(prek, gam, Ebuf);
  la_scan2<<<Bb * Hh, dim3(64), 0, stream>>>(Ebuf, gam, carry);

  la_post<<<Mm * Hh / 4, blk, 0, stream>>>(prek, preq, ogscr, gam, carry,
                                           mng, mnb, gng, gnb, bog, xbf);

  la_gemm<0><<<dim3(16, Mm / 128), blk, 0, stream>>>(
      xbf, wbf, wbf, wbf, d_out, d_out, d_out, Cc);
}